// Round 2
// baseline (95.122 us; speedup 1.0000x reference)
//
#include <hip/hip_runtime.h>

// LatencyEncoder: out[b,f,t] = (t == round(99*(1-sigmoid(x+0.01*noise)))) && sigmoid>0.5
// 1,048,576 pairs x 100 f32 -> 419.4 MB writes, 8.4 MB reads: write-BW bound.
//
// R1 structure: fill-kernel-like zero stream + L2-resident scatter.
//  - Each WAVE owns 64 consecutive pairs (25 KB of output).
//  - Lane computes its pair's latency in f64 (matches np ref exactly, R0 absmax=0).
//  - Wave zeroes its region with 25 coalesced float4 stores/lane (no LDS, no
//    selects, no divides in the hot loop -- same shape as rocclr fillBuffer
//    which measures 6.8-7.0 TB/s on this buffer).
//  - s_waitcnt vmcnt(0) (wave-local drain, no barrier), then each lane does one
//    conditional dword store of 1.0f into its own row. Target lines were written
//    by this wave microseconds ago -> L2-resident -> merge, no HBM RMW.

#define T 100
#define PAIRS_PER_WAVE 64
#define PAIRS_PER_BLOCK 256
#define F4_PER_LANE 25  // 64 pairs * 100 floats / 4 / 64 lanes

__global__ __launch_bounds__(256) void latency_encode_kernel(
    const float* __restrict__ x, const float* __restrict__ noise,
    float* __restrict__ out, int npairs) {
  const int tid  = threadIdx.x;
  const int lane = tid & 63;
  const int wave = tid >> 6;
  const long long waveBase =
      (long long)blockIdx.x * PAIRS_PER_BLOCK + (long long)wave * PAIRS_PER_WAVE;
  const long long p = waveBase + lane;

  // ---- per-lane latency in f64 (decision chain must match numpy ref) ----
  int lat = -1;
  if (p < npairs) {
    double xn = (double)x[p] + (double)noise[p] * 0.01;
    double s  = 1.0 / (1.0 + exp(-xn));
    int li = (int)rint((1.0 - s) * 99.0);
    li = li < 0 ? 0 : (li > 99 ? 99 : li);
    lat = (s > 0.5) ? li : -1;  // -1: no spike
  }

  // ---- zero the wave's contiguous 64x100-float region, coalesced float4 ----
  float4* o4 = (float4*)(out + waveBase * T);
  const float4 z = make_float4(0.f, 0.f, 0.f, 0.f);
  if (waveBase + PAIRS_PER_WAVE <= npairs) {
    // fast path: whole wave region in-bounds (always true for 256x4096)
#pragma unroll
    for (int k = 0; k < F4_PER_LANE; ++k) o4[lane + k * 64] = z;
  } else if (waveBase < npairs) {
    const long long lim4 = ((long long)npairs - waveBase) * T / 4;
#pragma unroll
    for (int k = 0; k < F4_PER_LANE; ++k) {
      const int fi4 = lane + k * 64;
      if (fi4 < lim4) o4[fi4] = z;
    }
  }

  // wave-local store drain: later scatter store is ordered after the zeroes
  asm volatile("s_waitcnt vmcnt(0)" ::: "memory");

  // ---- plant the spike (line is L2-resident: this wave just wrote it) ----
  if (lat >= 0) out[p * T + lat] = 1.0f;
}

extern "C" void kernel_launch(void* const* d_in, const int* in_sizes, int n_in,
                              void* d_out, int out_size, void* d_ws, size_t ws_size,
                              hipStream_t stream) {
  const float* x = (const float*)d_in[0];
  const float* noise = (const float*)d_in[1];
  float* out = (float*)d_out;
  const int npairs = in_sizes[0];  // 256*4096 = 1,048,576
  const int grid = (npairs + PAIRS_PER_BLOCK - 1) / PAIRS_PER_BLOCK;
  latency_encode_kernel<<<grid, 256, 0, stream>>>(x, noise, out, npairs);
}